// Round 3
// baseline (25.539 us; speedup 1.0000x reference)
//
#include <hip/hip_runtime.h>

// B=4, H=512, W=512 (from setup_inputs)
#define B_   4
#define H_   512
#define W_   512
#define HW_  (H_ * W_)

#define NBLK 512    // 128 spatial blocks x 4 batches
#define NTHR 256

// Semantics (verified exact in R2, absmax 0.0):
//   c0[p]  = #{b : !(pred[b,1,p] > pred[b,0,p])}                (argmax ties -> 0)
//   S[a,p] = pred[a,0,p]*c0 - pred[a,1,p]*(4-c0)
//   per neighbor (zero-padded gt & heights; pad counts as valid dry):
//     ign = (g != 255); gr = (g==0 ? -1 : 1); delta = hc - hn
//     kill = gr*delta > 0   (unifies flood_pos_elev / dry_neg_elev)
//     loss += ign && !kill ? (4 - gr*S) : 0;  n_valid += ign
//   out = loss / max(n_valid, 1)
__global__ __launch_bounds__(NTHR) void elev_fused(
    const float* __restrict__ pred,
    const float* __restrict__ hts,
    const float* __restrict__ gt,
    unsigned long long* __restrict__ partial,   // NBLK pairs
    unsigned int* __restrict__ counter,
    float* __restrict__ out)
{
    const int a     = blockIdx.x >> 7;              // batch handled by this block
    const int sb    = blockIdx.x & 127;             // spatial block
    const int chunk = sb * NTHR + threadIdx.x;      // [0, 32768): 8-px chunks
    const int px0   = chunk << 3;
    const int i     = px0 >> 9;
    const int j0    = px0 & (W_ - 1);

    // ---- cross-batch argmax counts for the 8 pixels ----
    int c0k[8] = {0, 0, 0, 0, 0, 0, 0, 0};
    #pragma unroll
    for (int b = 0; b < B_; ++b) {
        const float* p0p = pred + (size_t)(b * 2) * HW_ + px0;
        const float4 x0 = *(const float4*)(p0p);
        const float4 x1 = *(const float4*)(p0p + 4);
        const float4 y0 = *(const float4*)(p0p + HW_);
        const float4 y1 = *(const float4*)(p0p + HW_ + 4);
        c0k[0] += (y0.x > x0.x) ? 0 : 1;
        c0k[1] += (y0.y > x0.y) ? 0 : 1;
        c0k[2] += (y0.z > x0.z) ? 0 : 1;
        c0k[3] += (y0.w > x0.w) ? 0 : 1;
        c0k[4] += (y1.x > x1.x) ? 0 : 1;
        c0k[5] += (y1.y > x1.y) ? 0 : 1;
        c0k[6] += (y1.z > x1.z) ? 0 : 1;
        c0k[7] += (y1.w > x1.w) ? 0 : 1;
    }

    // ---- own batch S[k] (pred re-load hits L1) ----
    float S[8];
    {
        const float* p0p = pred + (size_t)(a * 2) * HW_ + px0;
        const float4 x0 = *(const float4*)(p0p);
        const float4 x1 = *(const float4*)(p0p + 4);
        const float4 y0 = *(const float4*)(p0p + HW_);
        const float4 y1 = *(const float4*)(p0p + HW_ + 4);
        const float xs[8] = {x0.x, x0.y, x0.z, x0.w, x1.x, x1.y, x1.z, x1.w};
        const float ys[8] = {y0.x, y0.y, y0.z, y0.w, y1.x, y1.y, y1.z, y1.w};
        #pragma unroll
        for (int k = 0; k < 8; ++k) {
            const float c0f = (float)c0k[k];
            S[k] = xs[k] * c0f - ys[k] * ((float)B_ - c0f);
        }
    }

    const float* hbase = hts + (size_t)a * HW_;
    const float* gbase = gt  + (size_t)a * HW_;

    // center heights
    float hc[8];
    {
        const float* hrow = hbase + (size_t)i * W_ + j0;
        const float4 h0 = *(const float4*)(hrow);
        const float4 h1 = *(const float4*)(hrow + 4);
        hc[0] = h0.x; hc[1] = h0.y; hc[2] = h0.z; hc[3] = h0.w;
        hc[4] = h1.x; hc[5] = h1.y; hc[6] = h1.z; hc[7] = h1.w;
    }

    const int  idxL = (j0 > 0) ? (j0 - 1) : 0;            // clamped, always in-bounds
    const int  idxR = (j0 < W_ - 8) ? (j0 + 8) : (W_ - 1);
    const bool lv   = (j0 > 0);
    const bool rv   = (j0 < W_ - 8);

    float lacc = 0.0f;
    int   vcnt = 0;

    #pragma unroll
    for (int dr = 0; dr < 3; ++dr) {
        const int  r    = i + dr - 1;
        const int  rc   = (r < 0) ? 0 : ((r > H_ - 1) ? (H_ - 1) : r);
        const bool rowv = (r == rc);
        const float* hrow = hbase + (size_t)rc * W_;
        const float* grow = gbase + (size_t)rc * W_;

        const float4 h0 = *(const float4*)(hrow + j0);
        const float4 h1 = *(const float4*)(hrow + j0 + 4);
        const float  hl = hrow[idxL];
        const float  hr2 = hrow[idxR];
        const float4 g0 = *(const float4*)(grow + j0);
        const float4 g1 = *(const float4*)(grow + j0 + 4);
        const float  gl = grow[idxL];
        const float  gr2 = grow[idxR];

        // 10-wide zero-padded windows (pad entries PARTICIPATE as g=0,h=0)
        float wh[10], wg[10];
        {
            const float hm[8] = {h0.x, h0.y, h0.z, h0.w, h1.x, h1.y, h1.z, h1.w};
            const float gm[8] = {g0.x, g0.y, g0.z, g0.w, g1.x, g1.y, g1.z, g1.w};
            #pragma unroll
            for (int c = 0; c < 8; ++c) {
                wh[c + 1] = rowv ? hm[c] : 0.0f;
                wg[c + 1] = rowv ? gm[c] : 0.0f;
            }
        }
        wh[0] = (rowv && lv) ? hl  : 0.0f;
        wg[0] = (rowv && lv) ? gl  : 0.0f;
        wh[9] = (rowv && rv) ? hr2 : 0.0f;
        wg[9] = (rowv && rv) ? gr2 : 0.0f;

        #pragma unroll
        for (int k = 0; k < 8; ++k) {
            #pragma unroll
            for (int d = 0; d < 3; ++d) {
                const float g     = wg[k + d];
                const float hn    = wh[k + d];
                const bool  ign   = (g != 255.0f);
                const float grv   = (g == 0.0f) ? -1.0f : 1.0f;
                const float delta = hc[k] - hn;
                const bool  keep  = !(grv * delta > 0.0f);
                const float sc    = 4.0f - grv * S[k];
                lacc += (ign && keep) ? sc : 0.0f;
                vcnt += ign ? 1 : 0;
            }
        }
    }

    // ---- block reduce ----
    double l = (double)lacc;
    double v = (double)vcnt;
    for (int off = 32; off > 0; off >>= 1) {
        l += __shfl_down(l, off, 64);
        v += __shfl_down(v, off, 64);
    }
    __shared__ double   s_l[NTHR / 64];
    __shared__ double   s_v[NTHR / 64];
    __shared__ unsigned s_old;
    const int wave = threadIdx.x >> 6;
    const int lane = threadIdx.x & 63;
    if (lane == 0) { s_l[wave] = l; s_v[wave] = v; }
    __syncthreads();
    if (threadIdx.x == 0) {
        const double bl = s_l[0] + s_l[1] + s_l[2] + s_l[3];
        const double bv = s_v[0] + s_v[1] + s_v[2] + s_v[3];
        atomicExch(&partial[2 * (size_t)blockIdx.x],     (unsigned long long)__double_as_longlong(bl));
        atomicExch(&partial[2 * (size_t)blockIdx.x + 1], (unsigned long long)__double_as_longlong(bv));
        __threadfence();                       // release: partials visible device-wide
        s_old = atomicAdd(counter, 1u);
    }
    __syncthreads();

    // ---- last block folds all partials in fixed index order (deterministic) ----
    if (s_old == NBLK - 1) {
        double tl = 0.0, tv = 0.0;
        #pragma unroll
        for (int q = 0; q < NBLK / NTHR; ++q) {
            const size_t idx = (size_t)(q * NTHR + threadIdx.x);
            // atomic read-of-0 => coherent cross-XCD read
            tl += __longlong_as_double((long long)atomicAdd(&partial[2 * idx],     0ull));
            tv += __longlong_as_double((long long)atomicAdd(&partial[2 * idx + 1], 0ull));
        }
        for (int off = 32; off > 0; off >>= 1) {
            tl += __shfl_down(tl, off, 64);
            tv += __shfl_down(tv, off, 64);
        }
        __syncthreads();   // s_l/s_v reuse
        if (lane == 0) { s_l[wave] = tl; s_v[wave] = tv; }
        __syncthreads();
        if (threadIdx.x == 0) {
            const double fl = s_l[0] + s_l[1] + s_l[2] + s_l[3];
            const double fv = s_v[0] + s_v[1] + s_v[2] + s_v[3];
            out[0] = (float)(fl / (fv > 1.0 ? fv : 1.0));
        }
    }
}

extern "C" void kernel_launch(void* const* d_in, const int* in_sizes, int n_in,
                              void* d_out, int out_size, void* d_ws, size_t ws_size,
                              hipStream_t stream) {
    const float* pred = (const float*)d_in[0];   // (4,2,512,512) f32
    const float* hts  = (const float*)d_in[1];   // (4,1,512,512) f32
    const float* gt   = (const float*)d_in[2];   // (4,1,512,512) f32
    float* out        = (float*)d_out;

    unsigned long long* partial = (unsigned long long*)d_ws;          // 512*2*8B = 8 KiB
    unsigned int* counter = (unsigned int*)((char*)d_ws + 8192);

    hipMemsetAsync(counter, 0, sizeof(unsigned int), stream);         // graph-capture-safe
    elev_fused<<<NBLK, NTHR, 0, stream>>>(pred, hts, gt, partial, counter, out);
}